// Round 1
// baseline (855.581 us; speedup 1.0000x reference)
//
#include <hip/hip_runtime.h>
#include <hip/hip_fp16.h>

#define DM 768
#define DS 12288
#define CAP 384          // per-row candidate capacity
#define CTHR 2.25f       // tau = CTHR * sigma_row  -> E[count] ~ 150, SD ~ 12
#define SLOTS 8          // per-row LDS slots per 256-col block (lambda~3.1, P(overflow)~0.5% -> exact spill path)
#define GRPM 16          // bm-supertile for XCD/L2 locality

typedef float    f32x4 __attribute__((ext_vector_type(4)));
typedef _Float16 f16x4 __attribute__((ext_vector_type(4)));
typedef _Float16 f16x8 __attribute__((ext_vector_type(8)));

typedef const __attribute__((address_space(1))) void* gas_t;
typedef __attribute__((address_space(3))) void* las_t;

__device__ __forceinline__ unsigned fkey(float f)
{
    unsigned u = __float_as_uint(f);
    return (u & 0x80000000u) ? ~u : (u | 0x80000000u);
}
__device__ __forceinline__ float ukey(unsigned k)
{
    return (k & 0x80000000u) ? __uint_as_float(k & 0x7FFFFFFFu) : __uint_as_float(~k);
}
__device__ __forceinline__ unsigned long long packci(float v, int col)
{
    return ((unsigned long long)fkey(v) << 32) | (unsigned long long)(0xFFFFFFFFu - (unsigned)col);
}

// ---------------------------------------------------------------- prep: x -> fp16 (x16), tau_row, zero cnt
__global__ __launch_bounds__(64)
void k_prep(const float* __restrict__ x, _Float16* __restrict__ xh,
            float* __restrict__ tau, unsigned* __restrict__ cnt)
{
    const int lane = threadIdx.x;
    const long row = blockIdx.x;
    const f32x4* xr = (const f32x4*)(x + row * DM);
    f32x4 v[3];
    float n2 = 0.f;
#pragma unroll
    for (int j = 0; j < 3; ++j) {
        v[j] = xr[lane + 64 * j];
#pragma unroll
        for (int c = 0; c < 4; ++c) n2 += v[j][c] * v[j][c];
    }
#pragma unroll
    for (int off = 32; off; off >>= 1) n2 += __shfl_down(n2, off);
    f16x4* xo = (f16x4*)(xh + row * DM);
#pragma unroll
    for (int j = 0; j < 3; ++j) {
        f16x4 h;
#pragma unroll
        for (int c = 0; c < 4; ++c) h[c] = (_Float16)(v[j][c] * 16.0f);
        xo[lane + 64 * j] = h;
    }
    if (lane == 0) {
        tau[row] = CTHR * sqrtf(n2 / 384.0f);   // sigma = ||x||/sqrt(384) for U(+-sqrt(6/768)) weights
        cnt[row] = 0u;
    }
}

// ---------------------------------------------------------------- W_enc -> fp16 (x256)
__global__ void k_split1(const float* __restrict__ src, _Float16* __restrict__ hi,
                         int n4, float scale)
{
    int i = blockIdx.x * 256 + threadIdx.x;
    if (i >= n4) return;
    f32x4 v = ((const f32x4*)src)[i];
    f16x4 h;
#pragma unroll
    for (int j = 0; j < 4; ++j) h[j] = (_Float16)(v[j] * scale);
    ((f16x4*)hi)[i] = h;
}

// ---------------------------------------------------------------- transpose W_dec [DM][DS] -> [DS][DM]
__global__ void k_transpose(const float* __restrict__ W, float* __restrict__ WT)
{
    __shared__ float tile[32][33];
    int bx = blockIdx.x;            // DS/32
    int by = blockIdx.y;            // DM/32
    int tx = threadIdx.x & 31;
    int ty = threadIdx.x >> 5;      // 0..7
#pragma unroll
    for (int j = 0; j < 4; ++j) {
        int d = by * 32 + ty + j * 8;
        tile[ty + j * 8][tx] = W[(long)d * DS + bx * 32 + tx];
    }
    __syncthreads();
#pragma unroll
    for (int j = 0; j < 4; ++j) {
        int s = bx * 32 + ty + j * 8;
        WT[(long)s * DM + by * 32 + tx] = tile[tx][ty + j * 8];
    }
}

// ---------------------------------------------------------------- encode GEMM: 256x256 tile, 8-wave, 8-phase
// counted-vmcnt schedule (T2 swizzle + T3/T4 + T5). 512 thr, 128 KiB LDS, 1 block/CU.
//
// LDS: sm[buf][A=0/B=1][half][128 rows x 8 slots x 8 f16], slot stored at (k_slot ^ (row&7))
// (pre-swizzled global source, linear LDS dest -> global_load_lds-compatible; both-sides swizzle).
//
// Phase plan per K-tile tk (buf c = tk&1), quadrants of the per-wave 128x64 output:
//   P0: ds A-lo(8) + B-lo(4) | stage A-half0 of tk+1 -> buf 1-c | MFMA (Mlo x Nlo)
//   P1: ds B-hi(4)           | stage A-half1 of tk+1 -> buf 1-c | MFMA (Mlo x Nhi)
//   P2: ds A-hi(8)           | stage B-half0 of tk+2 -> buf c   | MFMA (Mhi x Nlo)
//   P3:                      | stage B-half1 of tk+2 -> buf c   | MFMA (Mhi x Nhi) ; vmcnt(4)
// Deadness: buf c's B-region dead after P1, A-region after P2 -> stages above are race-free.
// vmcnt(4) leaves exactly the 2 newest B half-tiles in flight; everything older (all of tile
// tk+1) has landed before the next tile's ds_reads. Never drains to 0 in steady state.
#define BAR() do { __builtin_amdgcn_s_barrier(); asm volatile("" ::: "memory"); } while (0)

__global__ __launch_bounds__(512, 2)
void k_encode(const _Float16* __restrict__ Ah, const _Float16* __restrict__ Bh,
              const float* __restrict__ b_enc, const float* __restrict__ tau,
              unsigned* __restrict__ cnt, unsigned long long* __restrict__ cand)
{
    __shared__ __attribute__((aligned(16))) _Float16 sm[2][2][2][8192];   // 128 KiB

    const int t    = threadIdx.x;
    const int lane = t & 63;
    const int wave = t >> 6;         // 0..7
    const int wm   = wave >> 2;      // 0..1  M-half of the tile (also the A LDS half)
    const int wn   = wave & 3;       // 0..3  N-quarter (B half = wn>>1)
    const int lm   = lane & 15;
    const int quad = lane >> 4;

    // supertile swizzle: consecutive blocks sweep GRPM bm values -> per-XCD A-panel L2 residency
    const int id  = blockIdx.x;
    const int per = GRPM * (DS / 256);
    const int sid = id / per;
    const int rem = id % per;
    const int bm  = sid * GRPM + (rem & (GRPM - 1));
    const int bn  = rem / GRPM;

    // staging source (thread-fixed): row rS in [0,64), swizzled k-chunk gS
    const int rS = t >> 3;
    const int gS = (t & 7) ^ (rS & 7);
    const long baseA = (long)(bm * 256 + rS) * DM + gS * 8;
    const long baseB = (long)(bn * 256 + rS) * DM + gS * 8;

    _Float16* smB = &sm[0][0][0][0];

    auto STAGE = [&](int buf, int op, int h, int kt) {
        const _Float16* src = op ? Bh : Ah;
        const long off = (op ? baseB : baseA) + (long)h * (128 * DM) + kt * 64;
        _Float16* dst = smB + buf * 32768 + op * 16384 + h * 8192 + t * 8;
        __builtin_amdgcn_global_load_lds((gas_t)(src + off),           (las_t)dst,          16, 0, 0);
        __builtin_amdgcn_global_load_lds((gas_t)(src + off + 64 * DM), (las_t)(dst + 4096), 16, 0, 0);
    };

    f16x8 a[4][2];           // current M-half A fragments
    f16x8 b[4][2];           // all 4 N fragments of the wave's 64 cols
    f32x4 acc[8][4] = {};    // [M-frag 0..7][N-frag 0..3]
    const int s0 = ( quad      ^ (lane & 7)) * 8;
    const int s1 = ((quad + 4) ^ (lane & 7)) * 8;

    // prologue: tile0 {A0,A1,B0,B1}, tile1 {B0,B1}  (12 loads); wait for tile0 only
    STAGE(0, 0, 0, 0); STAGE(0, 0, 1, 0); STAGE(0, 1, 0, 0); STAGE(0, 1, 1, 0);
    STAGE(1, 1, 0, 1); STAGE(1, 1, 1, 1);
    asm volatile("s_waitcnt vmcnt(4)" ::: "memory");
    BAR();

    for (int tk = 0; tk < 12; ++tk) {
        const int c = tk & 1;
        const _Float16* rdA = smB + c * 32768 + wm * 8192 + lm * 64;
        const _Float16* rdB = smB + c * 32768 + 16384 + (wn >> 1) * 8192 + (wn & 1) * 4096 + lm * 64;

        // ---------------- P0
#pragma unroll
        for (int mt = 0; mt < 4; ++mt) {
            a[mt][0] = *(const f16x8*)(rdA + mt * 1024 + s0);
            a[mt][1] = *(const f16x8*)(rdA + mt * 1024 + s1);
        }
#pragma unroll
        for (int nt = 0; nt < 2; ++nt) {
            b[nt][0] = *(const f16x8*)(rdB + nt * 1024 + s0);
            b[nt][1] = *(const f16x8*)(rdB + nt * 1024 + s1);
        }
        if (tk < 11) STAGE(1 - c, 0, 0, tk + 1);
        asm volatile("s_waitcnt lgkmcnt(8)" ::: "memory");
        BAR();
        asm volatile("s_waitcnt lgkmcnt(0)" ::: "memory");
        __builtin_amdgcn_s_setprio(1);
#pragma unroll
        for (int kk = 0; kk < 2; ++kk)
#pragma unroll
            for (int mt = 0; mt < 4; ++mt)
#pragma unroll
                for (int nt = 0; nt < 2; ++nt)
                    acc[mt][nt] = __builtin_amdgcn_mfma_f32_16x16x32_f16(a[mt][kk], b[nt][kk], acc[mt][nt], 0, 0, 0);
        __builtin_amdgcn_s_setprio(0);
        BAR();

        // ---------------- P1
#pragma unroll
        for (int nt = 0; nt < 2; ++nt) {
            b[2 + nt][0] = *(const f16x8*)(rdB + (2 + nt) * 1024 + s0);
            b[2 + nt][1] = *(const f16x8*)(rdB + (2 + nt) * 1024 + s1);
        }
        if (tk < 11) STAGE(1 - c, 0, 1, tk + 1);
        BAR();
        asm volatile("s_waitcnt lgkmcnt(0)" ::: "memory");
        __builtin_amdgcn_s_setprio(1);
#pragma unroll
        for (int kk = 0; kk < 2; ++kk)
#pragma unroll
            for (int mt = 0; mt < 4; ++mt)
#pragma unroll
                for (int nt = 0; nt < 2; ++nt)
                    acc[mt][2 + nt] = __builtin_amdgcn_mfma_f32_16x16x32_f16(a[mt][kk], b[2 + nt][kk], acc[mt][2 + nt], 0, 0, 0);
        __builtin_amdgcn_s_setprio(0);
        BAR();

        // ---------------- P2
#pragma unroll
        for (int mt = 0; mt < 4; ++mt) {
            a[mt][0] = *(const f16x8*)(rdA + 4096 + mt * 1024 + s0);
            a[mt][1] = *(const f16x8*)(rdA + 4096 + mt * 1024 + s1);
        }
        if (tk < 10) STAGE(c, 1, 0, tk + 2);
        BAR();
        asm volatile("s_waitcnt lgkmcnt(0)" ::: "memory");
        __builtin_amdgcn_s_setprio(1);
#pragma unroll
        for (int kk = 0; kk < 2; ++kk)
#pragma unroll
            for (int mt = 0; mt < 4; ++mt)
#pragma unroll
                for (int nt = 0; nt < 2; ++nt)
                    acc[4 + mt][nt] = __builtin_amdgcn_mfma_f32_16x16x32_f16(a[mt][kk], b[nt][kk], acc[4 + mt][nt], 0, 0, 0);
        __builtin_amdgcn_s_setprio(0);
        BAR();

        // ---------------- P3
        if (tk < 10) STAGE(c, 1, 1, tk + 2);
        BAR();
        __builtin_amdgcn_s_setprio(1);
#pragma unroll
        for (int kk = 0; kk < 2; ++kk)
#pragma unroll
            for (int mt = 0; mt < 4; ++mt)
#pragma unroll
                for (int nt = 0; nt < 2; ++nt)
                    acc[4 + mt][2 + nt] = __builtin_amdgcn_mfma_f32_16x16x32_f16(a[mt][kk], b[2 + nt][kk], acc[4 + mt][2 + nt], 0, 0, 0);
        __builtin_amdgcn_s_setprio(0);
        if (tk < 10)       { asm volatile("s_waitcnt vmcnt(4)" ::: "memory"); }
        else if (tk == 10) { asm volatile("s_waitcnt vmcnt(0)" ::: "memory"); }
        BAR();
    }

    // ---- epilogue: candidate emit. Tile LDS is dead; carve srcnt/slist/stau out of it.
    __syncthreads();
    unsigned*           srcnt = (unsigned*)smB;                                   // 256 x 4B
    unsigned long long* slist = (unsigned long long*)((char*)smB + 1024);         // 256 x SLOTS x 8B
    float*              stau  = (float*)((char*)smB + 1024 + 256 * SLOTS * 8);    // 256 x 4B
    for (int j = t; j < 256; j += 512) { srcnt[j] = 0u; stau[j] = tau[bm * 256 + j]; }
    __syncthreads();

    const float inv = 1.0f / 4096.0f;   // undo x*16, w*256 scaling
#pragma unroll
    for (int nt = 0; nt < 4; ++nt) {
        int col = bn * 256 + wn * 64 + nt * 16 + lm;
        float bias = b_enc[col];
#pragma unroll
        for (int mo = 0; mo < 8; ++mo) {
            int rbase = wm * 128 + mo * 16 + quad * 4;
#pragma unroll
            for (int r = 0; r < 4; ++r) {
                float val = acc[mo][nt][r] * inv + bias;
                int rl = rbase + r;
                if (val > stau[rl]) {
                    unsigned s = atomicAdd(&srcnt[rl], 1u);
                    if (s < SLOTS) slist[rl * SLOTS + s] = packci(val, col);
                    else {          // rare overflow: exact global path
                        int row = bm * 256 + rl;
                        unsigned p = atomicAdd(&cnt[row], 1u);
                        if (p < CAP) cand[(long)row * CAP + p] = packci(val, col);
                    }
                }
            }
        }
    }
    __syncthreads();

    // ---- one parallel reservation round per block: lane t<256 owns row t
    if (t < 256) {
        unsigned n = srcnt[t]; n = n < SLOTS ? n : SLOTS;
        if (n) {
            int row = bm * 256 + t;
            unsigned base = atomicAdd(&cnt[row], n);
            for (unsigned j = 0; j < n; ++j)
                if (base + j < CAP)
                    cand[(long)row * CAP + base + j] = slist[t * SLOTS + j];
        }
    }
}

// ---------------------------------------------------------------- select + fp64 tie refine + scatter + decode
__global__ __launch_bounds__(256)
void k_select_decode(const unsigned long long* __restrict__ cand,
                     const unsigned* __restrict__ cnt,
                     const float* __restrict__ tau,
                     float* __restrict__ sparse, float* __restrict__ recon,
                     const float* __restrict__ WdT, const float* __restrict__ b_dec,
                     const int* __restrict__ kptr,
                     const float* __restrict__ x, const float* __restrict__ W_enc,
                     const float* __restrict__ b_enc)
{
    __shared__ unsigned long long sc[CAP];
    __shared__ unsigned bmap[DS / 32];      // winner bitmap (384 words)
    __shared__ float  win_v[64];
    __shared__ int    win_i[64];
    __shared__ float  unc_v[96];
    __shared__ int    unc_i[96];
    __shared__ double unc_d[96];
    __shared__ int    sh_cnt, sh_uc;
    __shared__ float  sh_vk;

    const int  t    = threadIdx.x;
    const int  lane = t & 63;
    const int  wave = t >> 6;
    const long row  = blockIdx.x;
    float* rowp = sparse + row * (long)DS;
    int kk = *kptr; kk = min(max(kk, 1), 64);
    int C = (int)cnt[row];
    if (t == 0) sh_uc = 0;
    for (int j = t; j < DS / 32; j += 256) bmap[j] = 0u;

    if (C >= kk && C <= CAP) {
        for (int j = t; j < C; j += 256) sc[j] = cand[row * CAP + j];
        __syncthreads();
    } else {
        // ---- exact fallback (expected never): recompute the row, bit-search threshold
        const float* xr = x + row * DM;
        for (int c0 = t; c0 < DS; c0 += 256) {
            const float* wr = W_enc + (long)c0 * DM;
            float s = b_enc[c0];
            for (int d = 0; d < DM; ++d) s += xr[d] * wr[d];
            rowp[c0] = s;                       // rowp as scratch; overwritten by bitmap store pass
        }
        __syncthreads();
        unsigned thr = 0;
        for (int b = 31; b >= 0; --b) {
            unsigned c2 = thr | (1u << b);
            if (t == 0) sh_cnt = 0;
            __syncthreads();
            for (int j = t; j < DS; j += 256)
                if (fkey(rowp[j]) >= c2) atomicAdd(&sh_cnt, 1);
            __syncthreads();
            if (sh_cnt >= kk) thr = c2;
            __syncthreads();
        }
        float tlo = ukey(thr) - 0.03f;
        if (t == 0) sh_cnt = 0;
        __syncthreads();
        for (int j = t; j < DS; j += 256) {
            float f = rowp[j];
            if (f >= tlo) {
                int p = atomicAdd(&sh_cnt, 1);
                if (p < CAP) sc[p] = packci(f, j);
            }
        }
        __syncthreads();
        C = min(sh_cnt, CAP);
    }

    // ---- wave-0 selection: kk rounds of 64-lane argmax over register-cached candidates
    if (t < 64) {
        unsigned long long e[CAP / 64];
#pragma unroll
        for (int j = 0; j < CAP / 64; ++j) { int p = t + 64 * j; e[j] = (p < C) ? sc[p] : 0ULL; }
        for (int r = 0; r < kk; ++r) {
            unsigned long long m = e[0];
#pragma unroll
            for (int j = 1; j < CAP / 64; ++j) if (e[j] > m) m = e[j];
#pragma unroll
            for (int off = 32; off; off >>= 1) {
                unsigned long long o = __shfl_down(m, off);
                if (o > m) m = o;
            }
            m = __shfl(m, 0);
#pragma unroll
            for (int j = 0; j < CAP / 64; ++j) if (e[j] == m) e[j] = 0ULL;
            if (t == 0) {
                if (m) {
                    win_v[r] = ukey((unsigned)(m >> 32));
                    win_i[r] = (int)(0xFFFFFFFFu - (unsigned)(m & 0xFFFFFFFFu));
                } else { win_v[r] = -3.0e38f; win_i[r] = r; }
            }
        }
        if (t == 0) sh_vk = win_v[kk - 1];
    }
    __syncthreads();

    // ---- fp64 refinement of near-boundary ties.
    // 1-product fp16 latent error: rms ~6e-4, <=~5e-3 at 8 sigma; EPS=0.012 covers all
    // possible boundary-crossers with 2.4x margin.
    const float vk  = sh_vk;
    const float EPS = 0.012f;
    for (int j = t; j < C; j += 256) {
        float f = ukey((unsigned)(sc[j] >> 32));
        if (fabsf(f - vk) <= EPS) {
            int p = atomicAdd(&sh_uc, 1);
            if (p < 96) { unc_v[p] = f; unc_i[p] = (int)(0xFFFFFFFFu - (unsigned)(sc[j] & 0xFFFFFFFFu)); }
        }
    }
    __syncthreads();
    const int un = min(sh_uc, 96);
    if (un > 1) {
        const float* xr = x + row * DM;
        for (int e = wave; e < un; e += 4) {
            const float* wr = W_enc + (long)unc_i[e] * DM;
            double s = 0.0;
            for (int d = lane; d < DM; d += 64) s += (double)xr[d] * (double)wr[d];
#pragma unroll
            for (int off = 32; off; off >>= 1) s += __shfl_down(s, off);
            if (lane == 0) unc_d[e] = s + (double)b_enc[unc_i[e]];
        }
        __syncthreads();
        if (t == 0) {
            int a = 0;
            for (int i = 0; i < kk; ++i)
                if (win_v[i] > vk + EPS) { win_v[a] = win_v[i]; win_i[a] = win_i[i]; ++a; }
            int need = kk - a;
            for (int s = 0; s < need; ++s) {
                int bj = -1, bi = 0x7fffffff; double bd = 0.0;
                for (int j = 0; j < un; ++j) {
                    if (unc_i[j] < 0) continue;
                    double dj = unc_d[j];
                    if (bj < 0 || dj > bd || (dj == bd && unc_i[j] < bi)) { bj = j; bd = dj; bi = unc_i[j]; }
                }
                win_v[a + s] = unc_v[bj]; win_i[a + s] = unc_i[bj];
                unc_i[bj] = -1;
            }
        }
        __syncthreads();
    }

    // ---- write sparse row in ONE pass: zeros merged with winners via bitmap
    if (t < kk) atomicOr(&bmap[win_i[t] >> 5], 1u << (win_i[t] & 31));
    __syncthreads();
#pragma unroll
    for (int j = 0; j < 12; ++j) {
        int c4 = j * 256 + t;                   // f32x4 chunk index
        unsigned bits = (bmap[c4 >> 3] >> ((c4 & 7) * 4)) & 0xFu;
        f32x4 o = {0.f, 0.f, 0.f, 0.f};
        if (bits) {
#pragma unroll
            for (int b = 0; b < 4; ++b)
                if (bits & (1u << b)) {
                    int col = c4 * 4 + b;
                    for (int i = 0; i < kk; ++i)
                        if (win_i[i] == col) { o[b] = win_v[i]; break; }
                }
        }
        __builtin_nontemporal_store(o, ((f32x4*)rowp) + c4);
    }

    // ---- decode: recon[row][d] = b_dec[d] + sum_i v_i * WdT[s_i][d]
    float a0 = b_dec[t], a1 = b_dec[t + 256], a2 = b_dec[t + 512];
#pragma unroll 4
    for (int i = 0; i < kk; ++i) {
        float val = win_v[i];
        const float* w = WdT + (long)win_i[i] * DM;
        a0 += val * w[t];
        a1 += val * w[t + 256];
        a2 += val * w[t + 512];
    }
    float* rr = recon + row * DM;
    __builtin_nontemporal_store(a0, rr + t);
    __builtin_nontemporal_store(a1, rr + t + 256);
    __builtin_nontemporal_store(a2, rr + t + 512);
}

// ---------------------------------------------------------------- launch
extern "C" void kernel_launch(void* const* d_in, const int* in_sizes, int n_in,
                              void* d_out, int out_size, void* d_ws, size_t ws_size,
                              hipStream_t stream)
{
    const float* x     = (const float*)d_in[0];
    const float* W_enc = (const float*)d_in[1];
    const float* b_enc = (const float*)d_in[2];
    const float* W_dec = (const float*)d_in[3];
    const float* b_dec = (const float*)d_in[4];
    const int*   kptr  = (const int*)d_in[5];

    const int dmodel = in_sizes[4];               // 768
    const int dsae   = in_sizes[2];               // 12288
    const int M      = in_sizes[0] / dmodel;      // 8192

    float* recon  = (float*)d_out;                          // [M][DM]
    float* sparse = (float*)d_out + (size_t)M * dmodel;     // [M][DS]

    char* ws = (char*)d_ws;
    _Float16* xh  = (_Float16*)ws;          ws += (size_t)M * dmodel * 2;
    _Float16* wh  = (_Float16*)ws;          ws += (size_t)dsae * dmodel * 2;
    float*    WdT = (float*)ws;             ws += (size_t)dsae * dmodel * 4;
    unsigned long long* cand = (unsigned long long*)ws; ws += (size_t)M * CAP * 8;
    unsigned* cnt = (unsigned*)ws;          ws += (size_t)M * 4;
    float*    tau = (float*)ws;             ws += (size_t)M * 4;

    const int n4w = dsae * dmodel / 4;
    k_prep<<<M, 64, 0, stream>>>(x, xh, tau, cnt);
    k_split1<<<(n4w + 255) / 256, 256, 0, stream>>>(W_enc, wh, n4w, 256.0f);
    k_transpose<<<dim3(dsae / 32, dmodel / 32), 256, 0, stream>>>(W_dec, WdT);
    k_encode<<<(M / 256) * (dsae / 256), 512, 0, stream>>>(xh, wh, b_enc, tau, cnt, cand);
    k_select_decode<<<M, 256, 0, stream>>>(cand, cnt, tau, sparse, recon, WdT, b_dec,
                                           kptr, x, W_enc, b_enc);
}

// Round 2
// 815.297 us; speedup vs baseline: 1.0494x; 1.0494x over previous
//
#include <hip/hip_runtime.h>
#include <hip/hip_fp16.h>

#define DM 768
#define DS 12288
#define CAP 384          // per-row candidate capacity
#define CTHR 2.25f       // tau = CTHR * sigma_row  -> E[count] ~ 150, SD ~ 12
#define SLOTS 6          // per-row LDS slots per 128-col block (overflow P ~ 9e-4 -> exact spill path)
#define GRPM 16          // bm-supertile for XCD/L2 locality

typedef float    f32x4 __attribute__((ext_vector_type(4)));
typedef _Float16 f16x4 __attribute__((ext_vector_type(4)));
typedef _Float16 f16x8 __attribute__((ext_vector_type(8)));

typedef const __attribute__((address_space(1))) void* gas_t;
typedef __attribute__((address_space(3))) void* las_t;

__device__ __forceinline__ unsigned fkey(float f)
{
    unsigned u = __float_as_uint(f);
    return (u & 0x80000000u) ? ~u : (u | 0x80000000u);
}
__device__ __forceinline__ float ukey(unsigned k)
{
    return (k & 0x80000000u) ? __uint_as_float(k & 0x7FFFFFFFu) : __uint_as_float(~k);
}
__device__ __forceinline__ unsigned long long packci(float v, int col)
{
    return ((unsigned long long)fkey(v) << 32) | (unsigned long long)(0xFFFFFFFFu - (unsigned)col);
}

// ---------------------------------------------------------------- prep: x -> fp16 (x16), tau_row, zero cnt
__global__ __launch_bounds__(64)
void k_prep(const float* __restrict__ x, _Float16* __restrict__ xh,
            float* __restrict__ tau, unsigned* __restrict__ cnt)
{
    const int lane = threadIdx.x;
    const long row = blockIdx.x;
    const f32x4* xr = (const f32x4*)(x + row * DM);
    f32x4 v[3];
    float n2 = 0.f;
#pragma unroll
    for (int j = 0; j < 3; ++j) {
        v[j] = xr[lane + 64 * j];
#pragma unroll
        for (int c = 0; c < 4; ++c) n2 += v[j][c] * v[j][c];
    }
#pragma unroll
    for (int off = 32; off; off >>= 1) n2 += __shfl_down(n2, off);
    f16x4* xo = (f16x4*)(xh + row * DM);
#pragma unroll
    for (int j = 0; j < 3; ++j) {
        f16x4 h;
#pragma unroll
        for (int c = 0; c < 4; ++c) h[c] = (_Float16)(v[j][c] * 16.0f);
        xo[lane + 64 * j] = h;
    }
    if (lane == 0) {
        tau[row] = CTHR * sqrtf(n2 / 384.0f);   // sigma = ||x||/sqrt(384) for U(+-sqrt(6/768)) weights
        cnt[row] = 0u;
    }
}

// ---------------------------------------------------------------- W_enc -> fp16 (x256)
__global__ void k_split1(const float* __restrict__ src, _Float16* __restrict__ hi,
                         int n4, float scale)
{
    int i = blockIdx.x * 256 + threadIdx.x;
    if (i >= n4) return;
    f32x4 v = ((const f32x4*)src)[i];
    f16x4 h;
#pragma unroll
    for (int j = 0; j < 4; ++j) h[j] = (_Float16)(v[j] * scale);
    ((f16x4*)hi)[i] = h;
}

// ---------------------------------------------------------------- transpose W_dec [DM][DS] -> fp16 [DS][DM]
// fp16 halves the decode-gather traffic (805 -> 402 MB) and the table (37.7 -> 18.9 MB,
// ~fits aggregate L2). Per-term recon error <= |v|*0.022*2^-11 ~ 7.5e-5 -> negligible.
__global__ void k_transpose(const float* __restrict__ W, _Float16* __restrict__ WT)
{
    __shared__ float tile[32][33];
    int bx = blockIdx.x;            // DS/32
    int by = blockIdx.y;            // DM/32
    int tx = threadIdx.x & 31;
    int ty = threadIdx.x >> 5;      // 0..7
#pragma unroll
    for (int j = 0; j < 4; ++j) {
        int d = by * 32 + ty + j * 8;
        tile[ty + j * 8][tx] = W[(long)d * DS + bx * 32 + tx];
    }
    __syncthreads();
#pragma unroll
    for (int j = 0; j < 4; ++j) {
        int s = bx * 32 + ty + j * 8;
        WT[(long)s * DM + by * 32 + tx] = (_Float16)tile[tx][ty + j * 8];
    }
}

// ---------------------------------------------------------------- encode GEMM + LDS-compacted candidate emit
// 1D grid with bm-supertile swizzle: consecutive blocks sweep 16 bm values, so each
// XCD (round-robin over dispatch index) keeps 2 A-panels L2-resident and B-panel
// L3 traffic drops ~2x vs bn-fastest order.
__global__ __launch_bounds__(256, 4)
void k_encode(const _Float16* __restrict__ Ah, const _Float16* __restrict__ Bh,
              const float* __restrict__ b_enc, const float* __restrict__ tau,
              unsigned* __restrict__ cnt, unsigned long long* __restrict__ cand)
{
    __shared__ _Float16 sAh[128 * 64];
    __shared__ _Float16 sBh[128 * 64];
    __shared__ float    stau[128];
    __shared__ unsigned srcnt[128];
    __shared__ unsigned long long slist[128 * SLOTS];

    const int t    = threadIdx.x;
    const int lane = t & 63;
    const int wave = t >> 6;
    const int id   = blockIdx.x;
    const int per  = GRPM * (DS / 128);          // blocks per supertile
    const int sid  = id / per;
    const int rem  = id % per;
    const int bm   = sid * GRPM + (rem & (GRPM - 1));
    const int bn   = rem / GRPM;
    const int wm   = (wave & 1) * 64;
    const int wn   = (wave >> 1) * 64;
    const int lm   = lane & 15;
    const int quad = lane >> 4;

    if (t < 128) { stau[t] = tau[bm * 128 + t]; srcnt[t] = 0u; }

    f32x4 acc[4][4] = {};

    for (int kt = 0; kt < DM / 64; ++kt) {
        if (kt) __syncthreads();
        const int kbase = kt * 64;
#pragma unroll
        for (int i = 0; i < 4; ++i) {
            int L = i * 256 + t;
            int r = L >> 3;             // tile row 0..127
            int s = L & 7;              // lds slot
            int g = s ^ (r & 7);        // global slot fetched into lds slot s
            long aoff = (long)(bm * 128 + r) * DM + kbase + g * 8;
            long boff = (long)(bn * 128 + r) * DM + kbase + g * 8;
            __builtin_amdgcn_global_load_lds((gas_t)(Ah + aoff), (las_t)&sAh[L * 8], 16, 0, 0);
            __builtin_amdgcn_global_load_lds((gas_t)(Bh + boff), (las_t)&sBh[L * 8], 16, 0, 0);
        }
        __syncthreads();

#pragma unroll
        for (int kc = 0; kc < 2; ++kc) {
            f16x8 a_h[4], b_h[4];
#pragma unroll
            for (int mt = 0; mt < 4; ++mt) {
                int m = wm + mt * 16 + lm;
                int slot = (kc * 4 + quad) ^ (m & 7);
                a_h[mt] = *(const f16x8*)&sAh[m * 64 + slot * 8];
            }
#pragma unroll
            for (int nt = 0; nt < 4; ++nt) {
                int n = wn + nt * 16 + lm;
                int slot = (kc * 4 + quad) ^ (n & 7);
                b_h[nt] = *(const f16x8*)&sBh[n * 64 + slot * 8];
            }
#pragma unroll
            for (int mt = 0; mt < 4; ++mt)
#pragma unroll
                for (int nt = 0; nt < 4; ++nt)
                    acc[mt][nt] = __builtin_amdgcn_mfma_f32_16x16x32_f16(a_h[mt], b_h[nt], acc[mt][nt], 0, 0, 0);
        }
    }

    // ---- candidate push into per-row LDS lists (no dependent global-atomic chains)
    const float inv = 1.0f / 4096.0f;   // undo x*16, w*256 scaling
#pragma unroll
    for (int nt = 0; nt < 4; ++nt) {
        int col = bn * 128 + wn + nt * 16 + lm;
        float bias = b_enc[col];
#pragma unroll
        for (int mt = 0; mt < 4; ++mt) {
            int rbase = wm + mt * 16 + quad * 4;
#pragma unroll
            for (int r = 0; r < 4; ++r) {
                float val = acc[mt][nt][r] * inv + bias;
                if (val > stau[rbase + r]) {
                    int rl = rbase + r;
                    unsigned s = atomicAdd(&srcnt[rl], 1u);
                    if (s < SLOTS) slist[rl * SLOTS + s] = packci(val, col);
                    else {          // rare overflow: exact global path
                        int row = bm * 128 + rl;
                        unsigned p = atomicAdd(&cnt[row], 1u);
                        if (p < CAP) cand[(long)row * CAP + p] = packci(val, col);
                    }
                }
            }
        }
    }
    __syncthreads();

    // ---- one parallel reservation round per block: lane t<128 owns row t
    if (t < 128) {
        unsigned n = srcnt[t]; n = n < SLOTS ? n : SLOTS;
        if (n) {
            int row = bm * 128 + t;
            unsigned base = atomicAdd(&cnt[row], n);
            for (unsigned j = 0; j < n; ++j)
                if (base + j < CAP)
                    cand[(long)row * CAP + base + j] = slist[t * SLOTS + j];
        }
    }
}

// ---------------------------------------------------------------- select + fp64 tie refine + scatter + decode
__global__ __launch_bounds__(256)
void k_select_decode(const unsigned long long* __restrict__ cand,
                     const unsigned* __restrict__ cnt,
                     const float* __restrict__ tau,
                     float* __restrict__ sparse, float* __restrict__ recon,
                     const _Float16* __restrict__ WdT, const float* __restrict__ b_dec,
                     const int* __restrict__ kptr,
                     const float* __restrict__ x, const float* __restrict__ W_enc,
                     const float* __restrict__ b_enc)
{
    __shared__ unsigned long long sc[CAP];
    __shared__ unsigned bmap[DS / 32];      // winner bitmap (384 words)
    __shared__ float  win_v[64];
    __shared__ int    win_i[64];
    __shared__ float  unc_v[96];
    __shared__ int    unc_i[96];
    __shared__ double unc_d[96];
    __shared__ int    sh_cnt, sh_uc;
    __shared__ float  sh_vk;

    const int  t    = threadIdx.x;
    const int  lane = t & 63;
    const int  wave = t >> 6;
    const long row  = blockIdx.x;
    float* rowp = sparse + row * (long)DS;
    int kk = *kptr; kk = min(max(kk, 1), 64);
    int C = (int)cnt[row];
    if (t == 0) sh_uc = 0;
    for (int j = t; j < DS / 32; j += 256) bmap[j] = 0u;

    if (C >= kk && C <= CAP) {
        for (int j = t; j < C; j += 256) sc[j] = cand[row * CAP + j];
        __syncthreads();
    } else {
        // ---- exact fallback (expected never): recompute the row, bit-search threshold
        const float* xr = x + row * DM;
        for (int c0 = t; c0 < DS; c0 += 256) {
            const float* wr = W_enc + (long)c0 * DM;
            float s = b_enc[c0];
            for (int d = 0; d < DM; ++d) s += xr[d] * wr[d];
            rowp[c0] = s;                       // rowp as scratch; overwritten by bitmap store pass
        }
        __syncthreads();
        unsigned thr = 0;
        for (int b = 31; b >= 0; --b) {
            unsigned c2 = thr | (1u << b);
            if (t == 0) sh_cnt = 0;
            __syncthreads();
            for (int j = t; j < DS; j += 256)
                if (fkey(rowp[j]) >= c2) atomicAdd(&sh_cnt, 1);
            __syncthreads();
            if (sh_cnt >= kk) thr = c2;
            __syncthreads();
        }
        float tlo = ukey(thr) - 0.03f;
        if (t == 0) sh_cnt = 0;
        __syncthreads();
        for (int j = t; j < DS; j += 256) {
            float f = rowp[j];
            if (f >= tlo) {
                int p = atomicAdd(&sh_cnt, 1);
                if (p < CAP) sc[p] = packci(f, j);
            }
        }
        __syncthreads();
        C = min(sh_cnt, CAP);
    }

    // ---- wave-0 selection: kk rounds of 64-lane argmax over register-cached candidates
    if (t < 64) {
        unsigned long long e[CAP / 64];
#pragma unroll
        for (int j = 0; j < CAP / 64; ++j) { int p = t + 64 * j; e[j] = (p < C) ? sc[p] : 0ULL; }
        for (int r = 0; r < kk; ++r) {
            unsigned long long m = e[0];
#pragma unroll
            for (int j = 1; j < CAP / 64; ++j) if (e[j] > m) m = e[j];
#pragma unroll
            for (int off = 32; off; off >>= 1) {
                unsigned long long o = __shfl_down(m, off);
                if (o > m) m = o;
            }
            m = __shfl(m, 0);
#pragma unroll
            for (int j = 0; j < CAP / 64; ++j) if (e[j] == m) e[j] = 0ULL;
            if (t == 0) {
                if (m) {
                    win_v[r] = ukey((unsigned)(m >> 32));
                    win_i[r] = (int)(0xFFFFFFFFu - (unsigned)(m & 0xFFFFFFFFu));
                } else { win_v[r] = -3.0e38f; win_i[r] = r; }
            }
        }
        if (t == 0) sh_vk = win_v[kk - 1];
    }
    __syncthreads();

    // ---- fp64 refinement of near-boundary ties.
    // 1-product fp16 latent error: rms ~6e-4, <=~5e-3 at 8 sigma; EPS=0.012 covers all
    // possible boundary-crossers with 2.4x margin.
    const float vk  = sh_vk;
    const float EPS = 0.012f;
    for (int j = t; j < C; j += 256) {
        float f = ukey((unsigned)(sc[j] >> 32));
        if (fabsf(f - vk) <= EPS) {
            int p = atomicAdd(&sh_uc, 1);
            if (p < 96) { unc_v[p] = f; unc_i[p] = (int)(0xFFFFFFFFu - (unsigned)(sc[j] & 0xFFFFFFFFu)); }
        }
    }
    __syncthreads();
    const int un = min(sh_uc, 96);
    if (un > 1) {
        const float* xr = x + row * DM;
        for (int e = wave; e < un; e += 4) {
            const float* wr = W_enc + (long)unc_i[e] * DM;
            double s = 0.0;
            for (int d = lane; d < DM; d += 64) s += (double)xr[d] * (double)wr[d];
#pragma unroll
            for (int off = 32; off; off >>= 1) s += __shfl_down(s, off);
            if (lane == 0) unc_d[e] = s + (double)b_enc[unc_i[e]];
        }
        __syncthreads();
        if (t == 0) {
            int a = 0;
            for (int i = 0; i < kk; ++i)
                if (win_v[i] > vk + EPS) { win_v[a] = win_v[i]; win_i[a] = win_i[i]; ++a; }
            int need = kk - a;
            for (int s = 0; s < need; ++s) {
                int bj = -1, bi = 0x7fffffff; double bd = 0.0;
                for (int j = 0; j < un; ++j) {
                    if (unc_i[j] < 0) continue;
                    double dj = unc_d[j];
                    if (bj < 0 || dj > bd || (dj == bd && unc_i[j] < bi)) { bj = j; bd = dj; bi = unc_i[j]; }
                }
                win_v[a + s] = unc_v[bj]; win_i[a + s] = unc_i[bj];
                unc_i[bj] = -1;
            }
        }
        __syncthreads();
    }

    // ---- write sparse row in ONE pass: zeros merged with winners via bitmap
    if (t < kk) atomicOr(&bmap[win_i[t] >> 5], 1u << (win_i[t] & 31));
    __syncthreads();
#pragma unroll
    for (int j = 0; j < 12; ++j) {
        int c4 = j * 256 + t;                   // f32x4 chunk index
        unsigned bits = (bmap[c4 >> 3] >> ((c4 & 7) * 4)) & 0xFu;
        f32x4 o = {0.f, 0.f, 0.f, 0.f};
        if (bits) {
#pragma unroll
            for (int b = 0; b < 4; ++b)
                if (bits & (1u << b)) {
                    int col = c4 * 4 + b;
                    for (int i = 0; i < kk; ++i)
                        if (win_i[i] == col) { o[b] = win_v[i]; break; }
                }
        }
        __builtin_nontemporal_store(o, ((f32x4*)rowp) + c4);
    }

    // ---- decode: recon[row][d] = b_dec[d] + sum_i v_i * WdT16[s_i][d]
    float a0 = b_dec[t], a1 = b_dec[t + 256], a2 = b_dec[t + 512];
#pragma unroll 4
    for (int i = 0; i < kk; ++i) {
        float val = win_v[i];
        const _Float16* w = WdT + (long)win_i[i] * DM;
        a0 += val * (float)w[t];
        a1 += val * (float)w[t + 256];
        a2 += val * (float)w[t + 512];
    }
    float* rr = recon + row * DM;
    __builtin_nontemporal_store(a0, rr + t);
    __builtin_nontemporal_store(a1, rr + t + 256);
    __builtin_nontemporal_store(a2, rr + t + 512);
}

// ---------------------------------------------------------------- launch
extern "C" void kernel_launch(void* const* d_in, const int* in_sizes, int n_in,
                              void* d_out, int out_size, void* d_ws, size_t ws_size,
                              hipStream_t stream)
{
    const float* x     = (const float*)d_in[0];
    const float* W_enc = (const float*)d_in[1];
    const float* b_enc = (const float*)d_in[2];
    const float* W_dec = (const float*)d_in[3];
    const float* b_dec = (const float*)d_in[4];
    const int*   kptr  = (const int*)d_in[5];

    const int dmodel = in_sizes[4];               // 768
    const int dsae   = in_sizes[2];               // 12288
    const int M      = in_sizes[0] / dmodel;      // 8192

    float* recon  = (float*)d_out;                          // [M][DM]
    float* sparse = (float*)d_out + (size_t)M * dmodel;     // [M][DS]

    char* ws = (char*)d_ws;
    _Float16* xh  = (_Float16*)ws;          ws += (size_t)M * dmodel * 2;
    _Float16* wh  = (_Float16*)ws;          ws += (size_t)dsae * dmodel * 2;
    _Float16* WdT = (_Float16*)ws;          ws += (size_t)dsae * dmodel * 2;
    unsigned long long* cand = (unsigned long long*)ws; ws += (size_t)M * CAP * 8;
    unsigned* cnt = (unsigned*)ws;          ws += (size_t)M * 4;
    float*    tau = (float*)ws;             ws += (size_t)M * 4;

    const int n4w = dsae * dmodel / 4;
    k_prep<<<M, 64, 0, stream>>>(x, xh, tau, cnt);
    k_split1<<<(n4w + 255) / 256, 256, 0, stream>>>(W_enc, wh, n4w, 256.0f);
    k_transpose<<<dim3(dsae / 32, dmodel / 32), 256, 0, stream>>>(W_dec, WdT);
    k_encode<<<(M / 128) * (dsae / 128), 256, 0, stream>>>(xh, wh, b_enc, tau, cnt, cand);
    k_select_decode<<<M, 256, 0, stream>>>(cand, cnt, tau, sparse, recon, WdT, b_dec,
                                           kptr, x, W_enc, b_enc);
}

// Round 4
// 806.095 us; speedup vs baseline: 1.0614x; 1.0114x over previous
//
#include <hip/hip_runtime.h>
#include <hip/hip_fp16.h>

#define DM 768
#define DS 12288
#define CAP 384          // per-row candidate capacity
#define CTHR 2.25f       // tau = CTHR * sigma_row  -> E[count] ~ 150, SD ~ 12
#define SLOTS 6          // per-row LDS slots per 128-col block (overflow P ~ 9e-4 -> exact spill path)
#define GRPM 16          // bm-supertile for XCD/L2 locality

typedef float    f32x4 __attribute__((ext_vector_type(4)));
typedef _Float16 f16x4 __attribute__((ext_vector_type(4)));
typedef _Float16 f16x8 __attribute__((ext_vector_type(8)));

typedef const __attribute__((address_space(1))) void* gas_t;
typedef __attribute__((address_space(3))) void* las_t;

__device__ __forceinline__ unsigned fkey(float f)
{
    unsigned u = __float_as_uint(f);
    return (u & 0x80000000u) ? ~u : (u | 0x80000000u);
}
__device__ __forceinline__ float ukey(unsigned k)
{
    return (k & 0x80000000u) ? __uint_as_float(k & 0x7FFFFFFFu) : __uint_as_float(~k);
}
__device__ __forceinline__ unsigned long long packci(float v, int col)
{
    return ((unsigned long long)fkey(v) << 32) | (unsigned long long)(0xFFFFFFFFu - (unsigned)col);
}

// ---------------------------------------------------------------- prep: x -> fp16 (x16), tau_row, zero cnt
// 4 rows per block (one per wave): fewer blocks, better CU occupancy than 1-wave blocks.
__global__ __launch_bounds__(256)
void k_prep(const float* __restrict__ x, _Float16* __restrict__ xh,
            float* __restrict__ tau, unsigned* __restrict__ cnt)
{
    const int lane = threadIdx.x & 63;
    const long row = (long)blockIdx.x * 4 + (threadIdx.x >> 6);
    const f32x4* xr = (const f32x4*)(x + row * DM);
    f32x4 v[3];
    float n2 = 0.f;
#pragma unroll
    for (int j = 0; j < 3; ++j) {
        v[j] = xr[lane + 64 * j];
#pragma unroll
        for (int c = 0; c < 4; ++c) n2 += v[j][c] * v[j][c];
    }
#pragma unroll
    for (int off = 32; off; off >>= 1) n2 += __shfl_down(n2, off);
    f16x4* xo = (f16x4*)(xh + row * DM);
#pragma unroll
    for (int j = 0; j < 3; ++j) {
        f16x4 h;
#pragma unroll
        for (int c = 0; c < 4; ++c) h[c] = (_Float16)(v[j][c] * 16.0f);
        xo[lane + 64 * j] = h;
    }
    if (lane == 0) {
        tau[row] = CTHR * sqrtf(n2 / 384.0f);   // sigma = ||x||/sqrt(384) for U(+-sqrt(6/768)) weights
        cnt[row] = 0u;
    }
}

// ---------------------------------------------------------------- W_enc -> fp16 (x256)
__global__ void k_split1(const float* __restrict__ src, _Float16* __restrict__ hi,
                         int n4, float scale)
{
    int i = blockIdx.x * 256 + threadIdx.x;
    if (i >= n4) return;
    f32x4 v = ((const f32x4*)src)[i];
    f16x4 h;
#pragma unroll
    for (int j = 0; j < 4; ++j) h[j] = (_Float16)(v[j] * scale);
    ((f16x4*)hi)[i] = h;
}

// ---------------------------------------------------------------- transpose W_dec [DM][DS] -> fp16 [DS][DM]
// fp16 halves the decode-gather traffic; per-term recon error <= |v|*0.022*2^-11 ~ 7.5e-5.
__global__ void k_transpose(const float* __restrict__ W, _Float16* __restrict__ WT)
{
    __shared__ float tile[32][33];
    int bx = blockIdx.x;            // DS/32
    int by = blockIdx.y;            // DM/32
    int tx = threadIdx.x & 31;
    int ty = threadIdx.x >> 5;      // 0..7
#pragma unroll
    for (int j = 0; j < 4; ++j) {
        int d = by * 32 + ty + j * 8;
        tile[ty + j * 8][tx] = W[(long)d * DS + bx * 32 + tx];
    }
    __syncthreads();
#pragma unroll
    for (int j = 0; j < 4; ++j) {
        int s = bx * 32 + ty + j * 8;
        WT[(long)s * DM + by * 32 + tx] = (_Float16)tile[tx][ty + j * 8];
    }
}

// ---------------------------------------------------------------- encode GEMM + LDS-compacted candidate emit
// 1D grid with bm-supertile swizzle: consecutive blocks sweep 16 bm values, so each
// XCD (round-robin over dispatch index) keeps 2 A-panels L2-resident and B-panel
// L3 traffic drops ~2x vs bn-fastest order.
__global__ __launch_bounds__(256, 4)
void k_encode(const _Float16* __restrict__ Ah, const _Float16* __restrict__ Bh,
              const float* __restrict__ b_enc, const float* __restrict__ tau,
              unsigned* __restrict__ cnt, unsigned long long* __restrict__ cand)
{
    __shared__ _Float16 sAh[128 * 64];
    __shared__ _Float16 sBh[128 * 64];
    __shared__ float    stau[128];
    __shared__ unsigned srcnt[128];
    __shared__ unsigned long long slist[128 * SLOTS];

    const int t    = threadIdx.x;
    const int lane = t & 63;
    const int wave = t >> 6;
    const int id   = blockIdx.x;
    const int per  = GRPM * (DS / 128);          // blocks per supertile
    const int sid  = id / per;
    const int rem  = id % per;
    const int bm   = sid * GRPM + (rem & (GRPM - 1));
    const int bn   = rem / GRPM;
    const int wm   = (wave & 1) * 64;
    const int wn   = (wave >> 1) * 64;
    const int lm   = lane & 15;
    const int quad = lane >> 4;

    if (t < 128) { stau[t] = tau[bm * 128 + t]; srcnt[t] = 0u; }

    f32x4 acc[4][4] = {};

    for (int kt = 0; kt < DM / 64; ++kt) {
        if (kt) __syncthreads();
        const int kbase = kt * 64;
#pragma unroll
        for (int i = 0; i < 4; ++i) {
            int L = i * 256 + t;
            int r = L >> 3;             // tile row 0..127
            int s = L & 7;              // lds slot
            int g = s ^ (r & 7);        // global slot fetched into lds slot s
            long aoff = (long)(bm * 128 + r) * DM + kbase + g * 8;
            long boff = (long)(bn * 128 + r) * DM + kbase + g * 8;
            __builtin_amdgcn_global_load_lds((gas_t)(Ah + aoff), (las_t)&sAh[L * 8], 16, 0, 0);
            __builtin_amdgcn_global_load_lds((gas_t)(Bh + boff), (las_t)&sBh[L * 8], 16, 0, 0);
        }
        __syncthreads();

#pragma unroll
        for (int kc = 0; kc < 2; ++kc) {
            f16x8 a_h[4], b_h[4];
#pragma unroll
            for (int mt = 0; mt < 4; ++mt) {
                int m = wm + mt * 16 + lm;
                int slot = (kc * 4 + quad) ^ (m & 7);
                a_h[mt] = *(const f16x8*)&sAh[m * 64 + slot * 8];
            }
#pragma unroll
            for (int nt = 0; nt < 4; ++nt) {
                int n = wn + nt * 16 + lm;
                int slot = (kc * 4 + quad) ^ (n & 7);
                b_h[nt] = *(const f16x8*)&sBh[n * 64 + slot * 8];
            }
#pragma unroll
            for (int mt = 0; mt < 4; ++mt)
#pragma unroll
                for (int nt = 0; nt < 4; ++nt)
                    acc[mt][nt] = __builtin_amdgcn_mfma_f32_16x16x32_f16(a_h[mt], b_h[nt], acc[mt][nt], 0, 0, 0);
        }
    }

    // ---- candidate push into per-row LDS lists (no dependent global-atomic chains)
    const float inv = 1.0f / 4096.0f;   // undo x*16, w*256 scaling
#pragma unroll
    for (int nt = 0; nt < 4; ++nt) {
        int col = bn * 128 + wn + nt * 16 + lm;
        float bias = b_enc[col];
#pragma unroll
        for (int mt = 0; mt < 4; ++mt) {
            int rbase = wm + mt * 16 + quad * 4;
#pragma unroll
            for (int r = 0; r < 4; ++r) {
                float val = acc[mt][nt][r] * inv + bias;
                if (val > stau[rbase + r]) {
                    int rl = rbase + r;
                    unsigned s = atomicAdd(&srcnt[rl], 1u);
                    if (s < SLOTS) slist[rl * SLOTS + s] = packci(val, col);
                    else {          // rare overflow: exact global path
                        int row = bm * 128 + rl;
                        unsigned p = atomicAdd(&cnt[row], 1u);
                        if (p < CAP) cand[(long)row * CAP + p] = packci(val, col);
                    }
                }
            }
        }
    }
    __syncthreads();

    // ---- one parallel reservation round per block: lane t<128 owns row t
    if (t < 128) {
        unsigned n = srcnt[t]; n = n < SLOTS ? n : SLOTS;
        if (n) {
            int row = bm * 128 + t;
            unsigned base = atomicAdd(&cnt[row], n);
            for (unsigned j = 0; j < n; ++j)
                if (base + j < CAP)
                    cand[(long)row * CAP + base + j] = slist[t * SLOTS + j];
        }
    }
}

// ---------------------------------------------------------------- select + fp64 tie refine + scatter + decode
__global__ __launch_bounds__(256)
void k_select_decode(const unsigned long long* __restrict__ cand,
                     const unsigned* __restrict__ cnt,
                     const float* __restrict__ tau,
                     float* __restrict__ sparse, float* __restrict__ recon,
                     const _Float16* __restrict__ WdT, const float* __restrict__ b_dec,
                     const int* __restrict__ kptr,
                     const float* __restrict__ x, const float* __restrict__ W_enc,
                     const float* __restrict__ b_enc)
{
    __shared__ unsigned long long sc[CAP];
    __shared__ unsigned bmap[DS / 32];      // winner bitmap (384 words)
    __shared__ float  win_v[64];
    __shared__ int    win_i[64];
    __shared__ float  unc_v[96];
    __shared__ int    unc_i[96];
    __shared__ double unc_d[96];
    __shared__ int    sh_cnt, sh_uc;
    __shared__ float  sh_vk;

    const int  t    = threadIdx.x;
    const int  lane = t & 63;
    const int  wave = t >> 6;
    const long row  = blockIdx.x;
    float* rowp = sparse + row * (long)DS;
    int kk = *kptr; kk = min(max(kk, 1), 64);
    int C = (int)cnt[row];
    if (t == 0) sh_uc = 0;
    for (int j = t; j < DS / 32; j += 256) bmap[j] = 0u;

    if (C >= kk && C <= CAP) {
        for (int j = t; j < C; j += 256) sc[j] = cand[row * CAP + j];
        __syncthreads();
    } else {
        // ---- exact fallback (expected never): recompute the row, bit-search threshold
        const float* xr = x + row * DM;
        for (int c0 = t; c0 < DS; c0 += 256) {
            const float* wr = W_enc + (long)c0 * DM;
            float s = b_enc[c0];
            for (int d = 0; d < DM; ++d) s += xr[d] * wr[d];
            rowp[c0] = s;                       // rowp as scratch; overwritten by bitmap store pass
        }
        __syncthreads();
        unsigned thr = 0;
        for (int b = 31; b >= 0; --b) {
            unsigned c2 = thr | (1u << b);
            if (t == 0) sh_cnt = 0;
            __syncthreads();
            for (int j = t; j < DS; j += 256)
                if (fkey(rowp[j]) >= c2) atomicAdd(&sh_cnt, 1);
            __syncthreads();
            if (sh_cnt >= kk) thr = c2;
            __syncthreads();
        }
        float tlo = ukey(thr) - 0.03f;
        if (t == 0) sh_cnt = 0;
        __syncthreads();
        for (int j = t; j < DS; j += 256) {
            float f = rowp[j];
            if (f >= tlo) {
                int p = atomicAdd(&sh_cnt, 1);
                if (p < CAP) sc[p] = packci(f, j);
            }
        }
        __syncthreads();
        C = min(sh_cnt, CAP);
    }

    // ---- wave-0 selection: kk rounds of 64-lane argmax over register-cached candidates
    if (t < 64) {
        unsigned long long e[CAP / 64];
#pragma unroll
        for (int j = 0; j < CAP / 64; ++j) { int p = t + 64 * j; e[j] = (p < C) ? sc[p] : 0ULL; }
        for (int r = 0; r < kk; ++r) {
            unsigned long long m = e[0];
#pragma unroll
            for (int j = 1; j < CAP / 64; ++j) if (e[j] > m) m = e[j];
#pragma unroll
            for (int off = 32; off; off >>= 1) {
                unsigned long long o = __shfl_down(m, off);
                if (o > m) m = o;
            }
            m = __shfl(m, 0);
#pragma unroll
            for (int j = 0; j < CAP / 64; ++j) if (e[j] == m) e[j] = 0ULL;
            if (t == 0) {
                if (m) {
                    win_v[r] = ukey((unsigned)(m >> 32));
                    win_i[r] = (int)(0xFFFFFFFFu - (unsigned)(m & 0xFFFFFFFFu));
                } else { win_v[r] = -3.0e38f; win_i[r] = r; }
            }
        }
        if (t == 0) sh_vk = win_v[kk - 1];
    }
    __syncthreads();

    // ---- fp64 refinement of near-boundary ties.
    // 1-product fp16 latent error: rms ~6e-4, <=~5e-3 at 8 sigma; EPS=0.012 covers all
    // possible boundary-crossers with 2.4x margin.
    const float vk  = sh_vk;
    const float EPS = 0.012f;
    for (int j = t; j < C; j += 256) {
        float f = ukey((unsigned)(sc[j] >> 32));
        if (fabsf(f - vk) <= EPS) {
            int p = atomicAdd(&sh_uc, 1);
            if (p < 96) { unc_v[p] = f; unc_i[p] = (int)(0xFFFFFFFFu - (unsigned)(sc[j] & 0xFFFFFFFFu)); }
        }
    }
    __syncthreads();
    const int un = min(sh_uc, 96);
    if (un > 1) {
        const float* xr = x + row * DM;
        for (int e = wave; e < un; e += 4) {
            const float* wr = W_enc + (long)unc_i[e] * DM;
            double s = 0.0;
            for (int d = lane; d < DM; d += 64) s += (double)xr[d] * (double)wr[d];
#pragma unroll
            for (int off = 32; off; off >>= 1) s += __shfl_down(s, off);
            if (lane == 0) unc_d[e] = s + (double)b_enc[unc_i[e]];
        }
        __syncthreads();
        if (t == 0) {
            int a = 0;
            for (int i = 0; i < kk; ++i)
                if (win_v[i] > vk + EPS) { win_v[a] = win_v[i]; win_i[a] = win_i[i]; ++a; }
            int need = kk - a;
            for (int s = 0; s < need; ++s) {
                int bj = -1, bi = 0x7fffffff; double bd = 0.0;
                for (int j = 0; j < un; ++j) {
                    if (unc_i[j] < 0) continue;
                    double dj = unc_d[j];
                    if (bj < 0 || dj > bd || (dj == bd && unc_i[j] < bi)) { bj = j; bd = dj; bi = unc_i[j]; }
                }
                win_v[a + s] = unc_v[bj]; win_i[a + s] = unc_i[bj];
                unc_i[bj] = -1;
            }
        }
        __syncthreads();
    }

    // ---- write sparse row in ONE pass: zeros merged with winners via bitmap
    if (t < kk) atomicOr(&bmap[win_i[t] >> 5], 1u << (win_i[t] & 31));
    __syncthreads();
#pragma unroll
    for (int j = 0; j < 12; ++j) {
        int c4 = j * 256 + t;                   // f32x4 chunk index
        unsigned bits = (bmap[c4 >> 3] >> ((c4 & 7) * 4)) & 0xFu;
        f32x4 o = {0.f, 0.f, 0.f, 0.f};
        if (bits) {
#pragma unroll
            for (int b = 0; b < 4; ++b)
                if (bits & (1u << b)) {
                    int col = c4 * 4 + b;
                    for (int i = 0; i < kk; ++i)
                        if (win_i[i] == col) { o[b] = win_v[i]; break; }
                }
        }
        __builtin_nontemporal_store(o, ((f32x4*)rowp) + c4);
    }

    // ---- decode: recon[row][d] = b_dec[d] + sum_i v_i * WdT16[s_i][d]
    // t < 192 owns dims [4t, 4t+4): f16x4 gather (8 B/lane, full-width transactions;
    // same per-dim f32 accumulation order as scalar version -> bit-identical recon).
    if (t < 192) {
        f32x4 a4 = ((const f32x4*)b_dec)[t];
#pragma unroll 4
        for (int i = 0; i < kk; ++i) {
            float val = win_v[i];
            f16x4 w4 = *(const f16x4*)(WdT + (long)win_i[i] * DM + 4 * t);
#pragma unroll
            for (int j = 0; j < 4; ++j) a4[j] += val * (float)w4[j];
        }
        float* rr = recon + row * DM;
        __builtin_nontemporal_store(a4, ((f32x4*)rr) + t);
    }
}

// ---------------------------------------------------------------- launch
extern "C" void kernel_launch(void* const* d_in, const int* in_sizes, int n_in,
                              void* d_out, int out_size, void* d_ws, size_t ws_size,
                              hipStream_t stream)
{
    const float* x     = (const float*)d_in[0];
    const float* W_enc = (const float*)d_in[1];
    const float* b_enc = (const float*)d_in[2];
    const float* W_dec = (const float*)d_in[3];
    const float* b_dec = (const float*)d_in[4];
    const int*   kptr  = (const int*)d_in[5];

    const int dmodel = in_sizes[4];               // 768
    const int dsae   = in_sizes[2];               // 12288
    const int M      = in_sizes[0] / dmodel;      // 8192

    float* recon  = (float*)d_out;                          // [M][DM]
    float* sparse = (float*)d_out + (size_t)M * dmodel;     // [M][DS]

    char* ws = (char*)d_ws;
    _Float16* xh  = (_Float16*)ws;          ws += (size_t)M * dmodel * 2;
    _Float16* wh  = (_Float16*)ws;          ws += (size_t)dsae * dmodel * 2;
    _Float16* WdT = (_Float16*)ws;          ws += (size_t)dsae * dmodel * 2;
    unsigned long long* cand = (unsigned long long*)ws; ws += (size_t)M * CAP * 8;
    unsigned* cnt = (unsigned*)ws;          ws += (size_t)M * 4;
    float*    tau = (float*)ws;             ws += (size_t)M * 4;

    const int n4w = dsae * dmodel / 4;
    k_prep<<<M / 4, 256, 0, stream>>>(x, xh, tau, cnt);
    k_split1<<<(n4w + 255) / 256, 256, 0, stream>>>(W_enc, wh, n4w, 256.0f);
    k_transpose<<<dim3(dsae / 32, dmodel / 32), 256, 0, stream>>>(W_dec, WdT);
    k_encode<<<(M / 128) * (dsae / 128), 256, 0, stream>>>(xh, wh, b_enc, tau, cnt, cand);
    k_select_decode<<<M, 256, 0, stream>>>(cand, cnt, tau, sparse, recon, WdT, b_dec,
                                           kptr, x, W_enc, b_enc);
}